// Round 12
// baseline (505.674 us; speedup 1.0000x reference)
//
#include <hip/hip_runtime.h>

#define PP 20000

typedef short short8 __attribute__((ext_vector_type(8)));
typedef float floatx4 __attribute__((ext_vector_type(4)));

// ---- bf16 split helpers: x ~= hi + lo, |err| <= 2^-18 |x| --------------------
__device__ __forceinline__ unsigned int bf16_rne_bits(float x){
    unsigned int xb = __float_as_uint(x);
    return (xb + 0x7FFFu + ((xb >> 16) & 1u)) & 0xFFFF0000u;
}
__device__ __forceinline__ void split2(float x, short &h, short &l){
    unsigned int hb = bf16_rne_bits(x);
    h = (short)(hb >> 16);
    float r = x - __uint_as_float(hb);
    l = (short)(bf16_rne_bits(r) >> 16);
}

// ---- pre-split weight images (exact LDS staging layouts) --------------------
__device__ __align__(16) short g_ff1[32*8192];
__device__ __align__(16) short g_ff2[16*8192];
__device__ __align__(16) short g_qkvo[4][4*8192];
// ---- f32 v-buffer: g_vvf[(p*128+o)*4] = (x,y,z,0) float4 (16 B per channel).
// NOTE (R11 lesson): v feeds VN-LN direction-normalize downstream; needs
// <=1e-4 relative error.  bf16 (2^-9) broke it; f32 is bit-exact vs R10.
__device__ __align__(16) float g_vvf[PP*128*4];

// ============================================================================
// One-time weight pre-split into LDS-image layouts.  Grid 64 x 256.
// ============================================================================
__global__ __launch_bounds__(256) void prep_weights(
    const float* __restrict__ Wq, const float* __restrict__ Wk,
    const float* __restrict__ Wv, const float* __restrict__ Wo,
    const float* __restrict__ W1, const float* __restrict__ Wd,
    const float* __restrict__ W2)
{
    const int tid = blockIdx.x*256 + threadIdx.x;     // 16384 threads
    for (int e = tid; e < 65536; e += 16384){
        int j = e & 7, kg = (e>>3) & 15, n = (e>>7) & 15, ch = e >> 11;
        int k = kg*8 + j, col = ch*16 + n;
        int pos = n*128 + ((kg ^ (n&7)) << 3) + j;
        short h, l;
        split2(W1[(size_t)k*512 + col], h, l);
        g_ff1[ch*8192 + pos]        = h;
        g_ff1[ch*8192 + 2048 + pos] = l;
        split2(Wd[(size_t)k*512 + col], h, l);
        g_ff1[ch*8192 + 4096 + pos] = h;
        g_ff1[ch*8192 + 6144 + pos] = l;
    }
    for (int e = tid; e < 65536; e += 16384){
        int w = e & 31, n2 = (e>>5) & 127, pair = e >> 12;
        int lslot = (w>>3) ^ ((n2>>1)&3);
        int k = pair*32 + lslot*8 + (w&7);
        short h, l; split2(W2[(size_t)k*128 + n2], h, l);
        g_ff2[pair*8192 + n2*32 + w]        = h;
        g_ff2[pair*8192 + 4096 + n2*32 + w] = l;
    }
    for (int e = tid; e < 65536; e += 16384){
        int w = e & 127, col = (e>>7) & 31, ch = (e>>12) & 3, wg = e >> 14;
        int lslot = (w>>3) ^ (col&7);
        int k = lslot*8 + (w&7);
        const float* Wsrc = (wg==0)?Wq:(wg==1)?Wk:(wg==2)?Wv:Wo;
        short h, l; split2(Wsrc[(size_t)k*128 + ch*32 + col], h, l);
        g_qkvo[wg][ch*8192 + col*128 + w]        = h;
        g_qkvo[wg][ch*8192 + 4096 + col*128 + w] = l;
    }
}

// ============================================================================
// VN linear via MFMA (bf16 hi+lo 3-term split), pre-split B images.
// 16 points/block (grid 1250), A-frags in registers; LDS pool 32 KB.
// VOUT=0: f32 out[p*384+o*3+i].  VOUT=1: f32 float4 g_vvf[(p*128+o)*4].
// ============================================================================
template<int VOUT>
__global__ __launch_bounds__(256) void vn_gemm_mfma_t(const float* __restrict__ in,
    int widx, float* __restrict__ out)
{
    __shared__ __align__(16) char pool[32768];
    short* Ysh = (short*)pool;            // scratch: 64*128 shorts = 16 KB
    short* Ysl = (short*)(pool + 16384);
    short* Bh  = (short*)pool;            // per-chunk: 4096 shorts
    short* Bl  = (short*)(pool + 8192);

    const int tid  = threadIdx.x;
    const int wv   = tid >> 6;
    const int lane = tid & 63;
    const int mrow = lane & 15;
    const int kgrp = lane >> 4;
    const int p0   = blockIdx.x * 16;

    for (int f = tid; f < 2048; f += 256){
        int row = (f >> 7)*4 + 3, k = f & 127;
        Ysh[row*128 + k] = 0; Ysl[row*128 + k] = 0;
    }
    #pragma unroll
    for (int t = 0; t < 6; ++t){
        int f = tid + t*256;
        float4 w4 = *(const float4*)(in + (size_t)p0*384 + f*4);
        int e = f*4, pl = e/384, rem = e - pl*384;
        float vv4[4] = {w4.x, w4.y, w4.z, w4.w};
        #pragma unroll
        for (int j=0;j<4;++j){
            int c = (rem+j)/3, i = (rem+j) - c*3;
            int row = pl*4 + i;
            int idx = row*128 + (((c>>3) ^ (row&7)) << 3) + (c&7);
            short h, l; split2(vv4[j], h, l);
            Ysh[idx] = h; Ysl[idx] = l;
        }
    }
    __syncthreads();
    short8 ahf[4], alf[4];
    {
        const int arow = wv*16 + mrow;
        #pragma unroll
        for (int ks=0;ks<4;++ks){
            int slot = ks*4 + kgrp;
            int aoff = arow*128 + ((slot ^ (arow&7)) << 3);
            ahf[ks] = *(const short8*)(Ysh + aoff);
            alf[ks] = *(const short8*)(Ysl + aoff);
        }
    }

    const short* gW = g_qkvo[widx];
    for (int ch = 0; ch < 4; ++ch){
        __syncthreads();
        #pragma unroll
        for (int t=0;t<4;++t)
            ((short8*)pool)[tid + t*256] =
                ((const short8*)(gW + ch*8192))[tid + t*256];
        __syncthreads();

        #pragma unroll
        for (int ntl=0; ntl<2; ++ntl){
            floatx4 acc = {0.f,0.f,0.f,0.f};
            const int lcol = ntl*16 + mrow;
            #pragma unroll
            for (int ks=0;ks<4;++ks){
                int slot = ks*4 + kgrp;
                int boff = lcol*128 + ((slot ^ (mrow&7)) << 3);
                short8 bh = *(const short8*)(Bh + boff);
                short8 bl = *(const short8*)(Bl + boff);
                acc = __builtin_amdgcn_mfma_f32_16x16x32_bf16(ahf[ks], bh, acc, 0,0,0);
                acc = __builtin_amdgcn_mfma_f32_16x16x32_bf16(ahf[ks], bl, acc, 0,0,0);
                acc = __builtin_amdgcn_mfma_f32_16x16x32_bf16(alf[ks], bh, acc, 0,0,0);
            }
            const int p = p0 + wv*4 + kgrp;
            const int o = ch*32 + ntl*16 + mrow;
            if (VOUT == 0){
                size_t base = (size_t)p*384 + (size_t)o*3;
                out[base    ] = acc[0];
                out[base + 1] = acc[1];
                out[base + 2] = acc[2];
            } else {
                float4 v4;
                v4.x = acc[0]; v4.y = acc[1]; v4.z = acc[2]; v4.w = 0.f;
                *(float4*)(g_vvf + ((size_t)p*128 + o)*4) = v4;
            }
        }
    }
}

// ============================================================================
// Wo GEMM + fused LN1: y = LN1(resid + in@Wo).  Keeps 8 per-lane outputs in
// registers; VN-LN reduction via shfl_xor within each 16-lane point group.
// ============================================================================
__global__ __launch_bounds__(256) void vn_gemm_ln_mfma(const float* __restrict__ in,
    const float* __restrict__ resid, const float* __restrict__ gamma,
    const float* __restrict__ beta, float* __restrict__ out)
{
    __shared__ __align__(16) char pool[32768];
    short* Ysh = (short*)pool;
    short* Ysl = (short*)(pool + 16384);
    short* Bh  = (short*)pool;
    short* Bl  = (short*)(pool + 8192);

    const int tid  = threadIdx.x;
    const int wv   = tid >> 6;
    const int lane = tid & 63;
    const int mrow = lane & 15;
    const int kgrp = lane >> 4;
    const int p0   = blockIdx.x * 16;

    for (int f = tid; f < 2048; f += 256){
        int row = (f >> 7)*4 + 3, k = f & 127;
        Ysh[row*128 + k] = 0; Ysl[row*128 + k] = 0;
    }
    #pragma unroll
    for (int t = 0; t < 6; ++t){
        int f = tid + t*256;
        float4 w4 = *(const float4*)(in + (size_t)p0*384 + f*4);
        int e = f*4, pl = e/384, rem = e - pl*384;
        float vv4[4] = {w4.x, w4.y, w4.z, w4.w};
        #pragma unroll
        for (int j=0;j<4;++j){
            int c = (rem+j)/3, i = (rem+j) - c*3;
            int row = pl*4 + i;
            int idx = row*128 + (((c>>3) ^ (row&7)) << 3) + (c&7);
            short h, l; split2(vv4[j], h, l);
            Ysh[idx] = h; Ysl[idx] = l;
        }
    }
    __syncthreads();
    short8 ahf[4], alf[4];
    {
        const int arow = wv*16 + mrow;
        #pragma unroll
        for (int ks=0;ks<4;++ks){
            int slot = ks*4 + kgrp;
            int aoff = arow*128 + ((slot ^ (arow&7)) << 3);
            ahf[ks] = *(const short8*)(Ysh + aoff);
            alf[ks] = *(const short8*)(Ysl + aoff);
        }
    }

    const int p = p0 + wv*4 + kgrp;
    float rx[8], ry[8], rz[8];
    const short* gW = g_qkvo[3];
    #pragma unroll
    for (int ch = 0; ch < 4; ++ch){
        __syncthreads();
        #pragma unroll
        for (int t=0;t<4;++t)
            ((short8*)pool)[tid + t*256] =
                ((const short8*)(gW + ch*8192))[tid + t*256];
        __syncthreads();

        #pragma unroll
        for (int ntl=0; ntl<2; ++ntl){
            floatx4 acc = {0.f,0.f,0.f,0.f};
            const int lcol = ntl*16 + mrow;
            #pragma unroll
            for (int ks=0;ks<4;++ks){
                int slot = ks*4 + kgrp;
                int boff = lcol*128 + ((slot ^ (mrow&7)) << 3);
                short8 bh = *(const short8*)(Bh + boff);
                short8 bl = *(const short8*)(Bl + boff);
                acc = __builtin_amdgcn_mfma_f32_16x16x32_bf16(ahf[ks], bh, acc, 0,0,0);
                acc = __builtin_amdgcn_mfma_f32_16x16x32_bf16(ahf[ks], bl, acc, 0,0,0);
                acc = __builtin_amdgcn_mfma_f32_16x16x32_bf16(alf[ks], bh, acc, 0,0,0);
            }
            const int s = ch*2 + ntl;
            const int o = ch*32 + ntl*16 + mrow;
            size_t base = (size_t)p*384 + (size_t)o*3;
            rx[s] = resid[base]   + acc[0];
            ry[s] = resid[base+1] + acc[1];
            rz[s] = resid[base+2] + acc[2];
        }
    }

    float nrm[8], s1 = 0.f, s2 = 0.f;
    #pragma unroll
    for (int s=0;s<8;++s){
        float n = sqrtf(rx[s]*rx[s] + ry[s]*ry[s] + rz[s]*rz[s]);
        nrm[s] = n; s1 += n; s2 += n*n;
    }
    #pragma unroll
    for (int m=1; m<16; m<<=1){
        s1 += __shfl_xor(s1, m);
        s2 += __shfl_xor(s2, m);
    }
    float mu  = s1*(1.f/128.f);
    float var = s2*(1.f/128.f) - mu*mu;
    float inv = rsqrtf(var + 1e-5f);
    #pragma unroll
    for (int s=0;s<8;++s){
        int o = (s>>1)*32 + (s&1)*16 + mrow;
        size_t base = (size_t)p*384 + (size_t)o*3;
        float nh = (nrm[s] - mu)*inv*gamma[o] + beta[o];
        float sc = nh/(nrm[s] + 1e-6f);
        out[base] = rx[s]*sc; out[base+1] = ry[s]*sc; out[base+2] = rz[s]*sc;
    }
}

// ============================================================================
// FUSED attention: scores + softmax + apply in one kernel (one block/point).
// Phase 1: q (own io row) + gathered k rows -> logits -> softmax -> att_s LDS.
// Phase 2: gather f32 v rows (g_vvf, float4/channel) -> tgt2 -> overwrite own
// io row.  q fully read in phase 1; barrier orders phase-2 writes. Race-free.
// v stays f32: bit-identical arithmetic to the R10 two-kernel version.
// ============================================================================
__global__ __launch_bounds__(128) void attn_fused(
    float* io, const float* __restrict__ kf,
    const float* __restrict__ sh, const float* __restrict__ dist, const int* __restrict__ idxp,
    const float* __restrict__ gw1, const float* __restrict__ gb1,
    const float* __restrict__ gw2, const float* __restrict__ gb2)
{
    const int p = blockIdx.x, c = threadIdx.x;
    __shared__ __align__(16) float dot_s[16*132];
    __shared__ __align__(16) float pos_s[16*132];
    __shared__ float sh_s[48];
    __shared__ int   nidx[16];
    __shared__ __align__(16) float w1t[8*132];
    __shared__ float w2_s[64], b1_s[8], b2_s[8];
    __shared__ float u2_s[16*8], logit_s[16*8];
    __shared__ float att_s[128];

    if (c < 16) nidx[c] = idxp[p*16 + c];
    if (c < 48) sh_s[c] = sh[(size_t)p*51 + 3 + c];
    #pragma unroll
    for (int f = c; f < 1024; f += 128){
        int th2 = f >> 7, cc2 = f & 127;
        w1t[th2*132 + cc2] = gw1[cc2*8 + th2];
    }
    if (c < 64) w2_s[c] = gw2[c];
    if (c < 8){ b1_s[c]=gb1[c]; b2_s[c]=gb2[c]; }
    size_t qa = (size_t)p*384 + c*3;
    float qx = io[qa], qy = io[qa+1], qz = io[qa+2];
    __syncthreads();

    for (int n=0;n<16;++n){
        size_t kbase = (size_t)nidx[n]*384 + c*3;
        float kx = kf[kbase], ky = kf[kbase+1], kz = kf[kbase+2];
        dot_s[n*132 + c] = kx*qx + ky*qy + kz*qz;
        pos_s[n*132 + c] = (kx-qx)*sh_s[n*3] + (ky-qy)*sh_s[n*3+1] + (kz-qz)*sh_s[n*3+2];
    }
    __syncthreads();

    const int tn = c >> 3, th = c & 7;
    const float* drow = dot_s + tn*132 + th*16;
    float4 d0 = *(const float4*)(drow);
    float4 d1 = *(const float4*)(drow + 4);
    float4 d2 = *(const float4*)(drow + 8);
    float4 d3 = *(const float4*)(drow + 12);
    float dsum = (d0.x+d0.y+d0.z+d0.w) + (d1.x+d1.y+d1.z+d1.w)
               + (d2.x+d2.y+d2.z+d2.w) + (d3.x+d3.y+d3.z+d3.w);

    float uj = b1_s[th];
    const float* prow = pos_s + tn*132;
    const float* wrow = w1t  + th*132;
    #pragma unroll 8
    for (int cc=0; cc<128; cc+=4){
        float4 pv = *(const float4*)(prow + cc);
        float4 wv = *(const float4*)(wrow + cc);
        uj = fmaf(pv.x, wv.x, uj);
        uj = fmaf(pv.y, wv.y, uj);
        uj = fmaf(pv.z, wv.z, uj);
        uj = fmaf(pv.w, wv.w, uj);
    }
    u2_s[tn*8+th] = fmaxf(uj, 0.f);
    __syncthreads();

    float l = b2_s[th];
    #pragma unroll
    for (int j=0;j<8;++j) l += u2_s[tn*8+j]*w2_s[j*8+th];
    l += dsum + dist[(size_t)p*128 + tn*8 + th];
    logit_s[tn*8+th] = l * 0.25f;
    __syncthreads();

    if (c < 8){
        float mx = -3.0e38f;
        #pragma unroll
        for (int n=0;n<16;++n) mx = fmaxf(mx, logit_s[n*8+c]);
        float e[16], ssum = 0.f;
        #pragma unroll
        for (int n=0;n<16;++n){ e[n] = __expf(logit_s[n*8+c]-mx); ssum += e[n]; }
        float inv = 1.f/ssum;
        #pragma unroll
        for (int n=0;n<16;++n) att_s[n*8+c] = e[n]*inv;
    }
    __syncthreads();

    // ---- phase 2: apply (v in f32 float4, one dwordx4 per channel) --------
    const int h = c >> 4;
    float ax=0.f, ay=0.f, az=0.f;
    #pragma unroll
    for (int n=0;n<16;++n){
        float wgt = att_s[n*8+h];
        float4 v4 = *(const float4*)(g_vvf + ((size_t)nidx[n]*128 + c)*4);
        ax += wgt*v4.x;
        ay += wgt*v4.y;
        az += wgt*v4.z;
    }
    size_t ob = (size_t)p*384 + c*3;
    io[ob] = ax; io[ob+1] = ay; io[ob+2] = az;
}

// ============================================================================
// Fused FF + LN2 via MFMA (grid 1250, 40 KB pool, pre-split weight images).
// ============================================================================
__global__ __launch_bounds__(256,2) void vn_ff_mfma(const float* __restrict__ in,
    const float* __restrict__ l2g, const float* __restrict__ l2b,
    float* __restrict__ out)
{
    __shared__ __align__(16) char pool[40960];
    short* Ws1h = (short*)(pool);             // 2048 shorts
    short* Ws1l = (short*)(pool + 4096);
    short* Wsdh = (short*)(pool + 8192);
    short* Wsdl = (short*)(pool + 12288);
    short* Ws2h = (short*)(pool + 16384);     // 4096 shorts
    short* Ws2l = (short*)(pool + 24576);
    short* Hsh  = (short*)(pool + 32768);     // 2048 shorts
    short* Hsl  = (short*)(pool + 36864);
    short* Ysh  = (short*)(pool);             // scratch overlay
    short* Ysl  = (short*)(pool + 16384);

    const int tid  = threadIdx.x;
    const int wv   = tid >> 6;
    const int lane = tid & 63;
    const int mrow = lane & 15;
    const int kgrp = lane >> 4;
    const int p0   = blockIdx.x * 16;

    for (int f = tid; f < 2048; f += 256){
        int row = (f >> 7)*4 + 3, k = f & 127;
        Ysh[row*128 + k] = 0; Ysl[row*128 + k] = 0;
    }
    #pragma unroll
    for (int t = 0; t < 6; ++t){
        int f = tid + t*256;
        float4 w4 = *(const float4*)(in + (size_t)p0*384 + f*4);
        int e = f*4, pl = e/384, rem = e - pl*384;
        float vv4[4] = {w4.x, w4.y, w4.z, w4.w};
        #pragma unroll
        for (int j=0;j<4;++j){
            int c = (rem+j)/3, i = (rem+j) - c*3;
            int row = pl*4 + i;
            int idx = row*128 + (((c>>3) ^ (row&7)) << 3) + (c&7);
            short h, l; split2(vv4[j], h, l);
            Ysh[idx] = h; Ysl[idx] = l;
        }
    }
    __syncthreads();
    short8 ahf[4], alf[4];
    {
        const int arow = wv*16 + mrow;
        #pragma unroll
        for (int ks=0;ks<4;++ks){
            int slot = ks*4 + kgrp;
            int aoff = arow*128 + ((slot ^ (arow&7)) << 3);
            ahf[ks] = *(const short8*)(Ysh + aoff);
            alf[ks] = *(const short8*)(Ysl + aoff);
        }
    }

    floatx4 acc2[8];
    #pragma unroll
    for (int nt=0;nt<8;++nt) acc2[nt] = (floatx4){0.f,0.f,0.f,0.f};

    for (int ch = 0; ch < 32; ++ch){
        __syncthreads();
        #pragma unroll
        for (int t=0;t<4;++t)
            ((short8*)pool)[tid + t*256] =
                ((const short8*)(g_ff1 + ch*8192))[tid + t*256];
        if ((ch & 1) == 0){
            #pragma unroll
            for (int t=0;t<4;++t)
                ((short8*)(pool + 16384))[tid + t*256] =
                    ((const short8*)(g_ff2 + (ch>>1)*8192))[tid + t*256];
        }
        __syncthreads();

        floatx4 aU = {0.f,0.f,0.f,0.f}, aD = {0.f,0.f,0.f,0.f};
        #pragma unroll
        for (int ks=0;ks<4;++ks){
            int slot = ks*4 + kgrp;
            int boff = mrow*128 + ((slot ^ (mrow&7)) << 3);
            short8 b1h = *(const short8*)(Ws1h + boff);
            short8 b1l = *(const short8*)(Ws1l + boff);
            short8 bdh = *(const short8*)(Wsdh + boff);
            short8 bdl = *(const short8*)(Wsdl + boff);
            aU = __builtin_amdgcn_mfma_f32_16x16x32_bf16(ahf[ks], b1h, aU, 0,0,0);
            aU = __builtin_amdgcn_mfma_f32_16x16x32_bf16(ahf[ks], b1l, aU, 0,0,0);
            aU = __builtin_amdgcn_mfma_f32_16x16x32_bf16(alf[ks], b1h, aU, 0,0,0);
            aD = __builtin_amdgcn_mfma_f32_16x16x32_bf16(ahf[ks], bdh, aD, 0,0,0);
            aD = __builtin_amdgcn_mfma_f32_16x16x32_bf16(ahf[ks], bdl, aD, 0,0,0);
            aD = __builtin_amdgcn_mfma_f32_16x16x32_bf16(alf[ks], bdh, aD, 0,0,0);
        }

        {
            float ux=aU[0], uy=aU[1], uz=aU[2];
            float dx=aD[0], dy=aD[1], dz=aD[2];
            float dot = ux*dx + uy*dy + uz*dz;
            float ksq = dx*dx + dy*dy + dz*dz;
            if (dot < 0.f){
                float fc = dot/(ksq + 1e-6f);
                ux -= fc*dx; uy -= fc*dy; uz -= fc*dz;
            }
            int col  = (ch & 1)*16 + mrow;
            int slot = col >> 3, cl = col & 7;
            float hv[4] = {ux, uy, uz, 0.f};
            #pragma unroll
            for (int r=0;r<4;++r){
                int row = wv*16 + kgrp*4 + r;
                int idx = row*32 + ((slot ^ ((row>>1)&3)) << 3) + cl;
                short h, l; split2(hv[r], h, l);
                Hsh[idx] = h; Hsl[idx] = l;
            }
        }

        if (ch & 1){
            const int arow2 = wv*16 + mrow;
            int aoff = arow2*32 + ((kgrp ^ ((arow2>>1)&3)) << 3);
            short8 ah = *(const short8*)(Hsh + aoff);
            short8 al = *(const short8*)(Hsl + aoff);
            #pragma unroll
            for (int nt=0;nt<8;++nt){
                int bcol = nt*16 + mrow;
                int boff = bcol*32 + ((kgrp ^ ((bcol>>1)&3)) << 3);
                short8 bh = *(const short8*)(Ws2h + boff);
                short8 bl = *(const short8*)(Ws2l + boff);
                acc2[nt] = __builtin_amdgcn_mfma_f32_16x16x32_bf16(ah, bh, acc2[nt], 0,0,0);
                acc2[nt] = __builtin_amdgcn_mfma_f32_16x16x32_bf16(ah, bl, acc2[nt], 0,0,0);
                acc2[nt] = __builtin_amdgcn_mfma_f32_16x16x32_bf16(al, bh, acc2[nt], 0,0,0);
            }
        }
    }

    const int p = p0 + wv*4 + kgrp;
    float nrm[8];
    float s1 = 0.f, s2 = 0.f;
    #pragma unroll
    for (int nt=0;nt<8;++nt){
        int o = nt*16 + mrow;
        size_t base = (size_t)p*384 + (size_t)o*3;
        float rx = in[base]   + acc2[nt][0];
        float ry = in[base+1] + acc2[nt][1];
        float rz = in[base+2] + acc2[nt][2];
        float n = sqrtf(rx*rx + ry*ry + rz*rz);
        nrm[nt] = n;
        s1 += n; s2 += n*n;
    }
    #pragma unroll
    for (int m=1; m<16; m<<=1){
        s1 += __shfl_xor(s1, m);
        s2 += __shfl_xor(s2, m);
    }
    float mu  = s1*(1.f/128.f);
    float var = s2*(1.f/128.f) - mu*mu;
    float inv = rsqrtf(var + 1e-5f);
    #pragma unroll
    for (int nt=0;nt<8;++nt){
        int o = nt*16 + mrow;
        size_t base = (size_t)p*384 + (size_t)o*3;
        float rx = in[base]   + acc2[nt][0];
        float ry = in[base+1] + acc2[nt][1];
        float rz = in[base+2] + acc2[nt][2];
        float nh = (nrm[nt] - mu)*inv*l2g[o] + l2b[o];
        float sc = nh/(nrm[nt] + 1e-6f);
        out[base] = rx*sc; out[base+1] = ry*sc; out[base+2] = rz*sc;
    }
}

// ============================================================================
extern "C" void kernel_launch(void* const* d_in, const int* in_sizes, int n_in,
                              void* d_out, int out_size, void* d_ws, size_t ws_size,
                              hipStream_t stream)
{
    const float* tgt  = (const float*)d_in[0];
    const float* mem  = (const float*)d_in[1];
    const float* sh   = (const float*)d_in[2];
    const float* dist = (const float*)d_in[3];
    const float* Wq   = (const float*)d_in[4];
    const float* Wk   = (const float*)d_in[5];
    const float* Wv   = (const float*)d_in[6];
    const float* Wo   = (const float*)d_in[7];
    const float* gw1  = (const float*)d_in[8];
    const float* gb1  = (const float*)d_in[9];
    const float* gw2  = (const float*)d_in[10];
    const float* gb2  = (const float*)d_in[11];
    const float* ln1g = (const float*)d_in[12];
    const float* ln1b = (const float*)d_in[13];
    const float* ln2g = (const float*)d_in[14];
    const float* ln2b = (const float*)d_in[15];
    const float* fw1  = (const float*)d_in[16];
    const float* fd1  = (const float*)d_in[17];
    const float* fw2  = (const float*)d_in[18];
    const int*   idx  = (const int*)d_in[19];

    float* wsf = (float*)d_ws;
    float* outf = (float*)d_out;

    prep_weights<<<64,256,0,stream>>>(Wq, Wk, Wv, Wo, fw1, fd1, fw2);

    vn_gemm_mfma_t<0><<<1250,256,0,stream>>>(mem, 1, wsf);            // kb = mem@Wk (f32 -> ws)
    vn_gemm_mfma_t<1><<<1250,256,0,stream>>>(mem, 2, nullptr);        // vv = mem@Wv (f32 -> g_vvf)
    vn_gemm_mfma_t<0><<<1250,256,0,stream>>>(tgt, 0, outf);           // q  = tgt@Wq (f32 -> d_out)
    // fused attention: logits+softmax+apply; overwrites own q rows with tgt2
    attn_fused<<<PP,128,0,stream>>>(outf, wsf, sh, dist, idx, gw1, gb1, gw2, gb2);
    // fused Wo GEMM + LN1: y = LN1(tgt + tgt2@Wo) -> ws
    vn_gemm_ln_mfma<<<1250,256,0,stream>>>(outf, tgt, ln1g, ln1b, wsf);
    // fused FF + LN2: reads y (ws), writes FINAL output to d_out
    vn_ff_mfma<<<1250,256,0,stream>>>(wsf, ln2g, ln2b, outf);
}

// Round 13
// 478.660 us; speedup vs baseline: 1.0564x; 1.0564x over previous
//
#include <hip/hip_runtime.h>

#define PP 20000

typedef short short8 __attribute__((ext_vector_type(8)));
typedef float floatx4 __attribute__((ext_vector_type(4)));

// ---- bf16 split helpers: x ~= hi + lo, |err| <= 2^-18 |x| --------------------
__device__ __forceinline__ unsigned int bf16_rne_bits(float x){
    unsigned int xb = __float_as_uint(x);
    return (xb + 0x7FFFu + ((xb >> 16) & 1u)) & 0xFFFF0000u;
}
__device__ __forceinline__ void split2(float x, short &h, short &l){
    unsigned int hb = bf16_rne_bits(x);
    h = (short)(hb >> 16);
    float r = x - __uint_as_float(hb);
    l = (short)(bf16_rne_bits(r) >> 16);
}

// ---- pre-split weight images (exact LDS staging layouts) --------------------
__device__ __align__(16) short g_ff1[32*8192];
__device__ __align__(16) short g_ff2[16*8192];
__device__ __align__(16) short g_qkvo[4][4*8192];
// ---- f32 v-buffer, PACKED float3 rows (p*384 + o*3): same 1536 B/row as k.
// R11 lesson: v feeds VN-LN direction-normalize; needs <=1e-4 rel error -> f32.
// R12 lesson: float4 padding cost +160 MB gather traffic; keep rows packed.
__device__ __align__(16) float g_vvf[PP*384];

// ============================================================================
// One-time weight pre-split into LDS-image layouts.  Grid 64 x 256.
// ============================================================================
__global__ __launch_bounds__(256) void prep_weights(
    const float* __restrict__ Wq, const float* __restrict__ Wk,
    const float* __restrict__ Wv, const float* __restrict__ Wo,
    const float* __restrict__ W1, const float* __restrict__ Wd,
    const float* __restrict__ W2)
{
    const int tid = blockIdx.x*256 + threadIdx.x;     // 16384 threads
    for (int e = tid; e < 65536; e += 16384){
        int j = e & 7, kg = (e>>3) & 15, n = (e>>7) & 15, ch = e >> 11;
        int k = kg*8 + j, col = ch*16 + n;
        int pos = n*128 + ((kg ^ (n&7)) << 3) + j;
        short h, l;
        split2(W1[(size_t)k*512 + col], h, l);
        g_ff1[ch*8192 + pos]        = h;
        g_ff1[ch*8192 + 2048 + pos] = l;
        split2(Wd[(size_t)k*512 + col], h, l);
        g_ff1[ch*8192 + 4096 + pos] = h;
        g_ff1[ch*8192 + 6144 + pos] = l;
    }
    for (int e = tid; e < 65536; e += 16384){
        int w = e & 31, n2 = (e>>5) & 127, pair = e >> 12;
        int lslot = (w>>3) ^ ((n2>>1)&3);
        int k = pair*32 + lslot*8 + (w&7);
        short h, l; split2(W2[(size_t)k*128 + n2], h, l);
        g_ff2[pair*8192 + n2*32 + w]        = h;
        g_ff2[pair*8192 + 4096 + n2*32 + w] = l;
    }
    for (int e = tid; e < 65536; e += 16384){
        int w = e & 127, col = (e>>7) & 31, ch = (e>>12) & 3, wg = e >> 14;
        int lslot = (w>>3) ^ (col&7);
        int k = lslot*8 + (w&7);
        const float* Wsrc = (wg==0)?Wq:(wg==1)?Wk:(wg==2)?Wv:Wo;
        short h, l; split2(Wsrc[(size_t)k*128 + ch*32 + col], h, l);
        g_qkvo[wg][ch*8192 + col*128 + w]        = h;
        g_qkvo[wg][ch*8192 + 4096 + col*128 + w] = l;
    }
}

// ============================================================================
// VN linear via MFMA (bf16 hi+lo 3-term split), pre-split B images.
// 16 points/block (grid 1250), A-frags in registers; LDS pool 32 KB.
// VOUT=0: writes to `out` arg.  VOUT=1: writes to g_vvf.  Both use the packed
// p*384 + o*3 layout (identical code path, identical bits).
// ============================================================================
template<int VOUT>
__global__ __launch_bounds__(256) void vn_gemm_mfma_t(const float* __restrict__ in,
    int widx, float* __restrict__ out)
{
    __shared__ __align__(16) char pool[32768];
    short* Ysh = (short*)pool;            // scratch: 64*128 shorts = 16 KB
    short* Ysl = (short*)(pool + 16384);
    short* Bh  = (short*)pool;            // per-chunk: 4096 shorts
    short* Bl  = (short*)(pool + 8192);

    const int tid  = threadIdx.x;
    const int wv   = tid >> 6;
    const int lane = tid & 63;
    const int mrow = lane & 15;
    const int kgrp = lane >> 4;
    const int p0   = blockIdx.x * 16;

    for (int f = tid; f < 2048; f += 256){
        int row = (f >> 7)*4 + 3, k = f & 127;
        Ysh[row*128 + k] = 0; Ysl[row*128 + k] = 0;
    }
    #pragma unroll
    for (int t = 0; t < 6; ++t){
        int f = tid + t*256;
        float4 w4 = *(const float4*)(in + (size_t)p0*384 + f*4);
        int e = f*4, pl = e/384, rem = e - pl*384;
        float vv4[4] = {w4.x, w4.y, w4.z, w4.w};
        #pragma unroll
        for (int j=0;j<4;++j){
            int c = (rem+j)/3, i = (rem+j) - c*3;
            int row = pl*4 + i;
            int idx = row*128 + (((c>>3) ^ (row&7)) << 3) + (c&7);
            short h, l; split2(vv4[j], h, l);
            Ysh[idx] = h; Ysl[idx] = l;
        }
    }
    __syncthreads();
    short8 ahf[4], alf[4];
    {
        const int arow = wv*16 + mrow;
        #pragma unroll
        for (int ks=0;ks<4;++ks){
            int slot = ks*4 + kgrp;
            int aoff = arow*128 + ((slot ^ (arow&7)) << 3);
            ahf[ks] = *(const short8*)(Ysh + aoff);
            alf[ks] = *(const short8*)(Ysl + aoff);
        }
    }

    const short* gW = g_qkvo[widx];
    for (int ch = 0; ch < 4; ++ch){
        __syncthreads();
        #pragma unroll
        for (int t=0;t<4;++t)
            ((short8*)pool)[tid + t*256] =
                ((const short8*)(gW + ch*8192))[tid + t*256];
        __syncthreads();

        #pragma unroll
        for (int ntl=0; ntl<2; ++ntl){
            floatx4 acc = {0.f,0.f,0.f,0.f};
            const int lcol = ntl*16 + mrow;
            #pragma unroll
            for (int ks=0;ks<4;++ks){
                int slot = ks*4 + kgrp;
                int boff = lcol*128 + ((slot ^ (mrow&7)) << 3);
                short8 bh = *(const short8*)(Bh + boff);
                short8 bl = *(const short8*)(Bl + boff);
                acc = __builtin_amdgcn_mfma_f32_16x16x32_bf16(ahf[ks], bh, acc, 0,0,0);
                acc = __builtin_amdgcn_mfma_f32_16x16x32_bf16(ahf[ks], bl, acc, 0,0,0);
                acc = __builtin_amdgcn_mfma_f32_16x16x32_bf16(alf[ks], bh, acc, 0,0,0);
            }
            const int p = p0 + wv*4 + kgrp;
            const int o = ch*32 + ntl*16 + mrow;
            size_t base = (size_t)p*384 + (size_t)o*3;
            float* dst = (VOUT == 0) ? out : g_vvf;
            dst[base    ] = acc[0];
            dst[base + 1] = acc[1];
            dst[base + 2] = acc[2];
        }
    }
}

// ============================================================================
// Wo GEMM + fused LN1: y = LN1(resid + in@Wo).  Keeps 8 per-lane outputs in
// registers; VN-LN reduction via shfl_xor within each 16-lane point group.
// ============================================================================
__global__ __launch_bounds__(256) void vn_gemm_ln_mfma(const float* __restrict__ in,
    const float* __restrict__ resid, const float* __restrict__ gamma,
    const float* __restrict__ beta, float* __restrict__ out)
{
    __shared__ __align__(16) char pool[32768];
    short* Ysh = (short*)pool;
    short* Ysl = (short*)(pool + 16384);
    short* Bh  = (short*)pool;
    short* Bl  = (short*)(pool + 8192);

    const int tid  = threadIdx.x;
    const int wv   = tid >> 6;
    const int lane = tid & 63;
    const int mrow = lane & 15;
    const int kgrp = lane >> 4;
    const int p0   = blockIdx.x * 16;

    for (int f = tid; f < 2048; f += 256){
        int row = (f >> 7)*4 + 3, k = f & 127;
        Ysh[row*128 + k] = 0; Ysl[row*128 + k] = 0;
    }
    #pragma unroll
    for (int t = 0; t < 6; ++t){
        int f = tid + t*256;
        float4 w4 = *(const float4*)(in + (size_t)p0*384 + f*4);
        int e = f*4, pl = e/384, rem = e - pl*384;
        float vv4[4] = {w4.x, w4.y, w4.z, w4.w};
        #pragma unroll
        for (int j=0;j<4;++j){
            int c = (rem+j)/3, i = (rem+j) - c*3;
            int row = pl*4 + i;
            int idx = row*128 + (((c>>3) ^ (row&7)) << 3) + (c&7);
            short h, l; split2(vv4[j], h, l);
            Ysh[idx] = h; Ysl[idx] = l;
        }
    }
    __syncthreads();
    short8 ahf[4], alf[4];
    {
        const int arow = wv*16 + mrow;
        #pragma unroll
        for (int ks=0;ks<4;++ks){
            int slot = ks*4 + kgrp;
            int aoff = arow*128 + ((slot ^ (arow&7)) << 3);
            ahf[ks] = *(const short8*)(Ysh + aoff);
            alf[ks] = *(const short8*)(Ysl + aoff);
        }
    }

    const int p = p0 + wv*4 + kgrp;
    float rx[8], ry[8], rz[8];
    const short* gW = g_qkvo[3];
    #pragma unroll
    for (int ch = 0; ch < 4; ++ch){
        __syncthreads();
        #pragma unroll
        for (int t=0;t<4;++t)
            ((short8*)pool)[tid + t*256] =
                ((const short8*)(gW + ch*8192))[tid + t*256];
        __syncthreads();

        #pragma unroll
        for (int ntl=0; ntl<2; ++ntl){
            floatx4 acc = {0.f,0.f,0.f,0.f};
            const int lcol = ntl*16 + mrow;
            #pragma unroll
            for (int ks=0;ks<4;++ks){
                int slot = ks*4 + kgrp;
                int boff = lcol*128 + ((slot ^ (mrow&7)) << 3);
                short8 bh = *(const short8*)(Bh + boff);
                short8 bl = *(const short8*)(Bl + boff);
                acc = __builtin_amdgcn_mfma_f32_16x16x32_bf16(ahf[ks], bh, acc, 0,0,0);
                acc = __builtin_amdgcn_mfma_f32_16x16x32_bf16(ahf[ks], bl, acc, 0,0,0);
                acc = __builtin_amdgcn_mfma_f32_16x16x32_bf16(alf[ks], bh, acc, 0,0,0);
            }
            const int s = ch*2 + ntl;
            const int o = ch*32 + ntl*16 + mrow;
            size_t base = (size_t)p*384 + (size_t)o*3;
            rx[s] = resid[base]   + acc[0];
            ry[s] = resid[base+1] + acc[1];
            rz[s] = resid[base+2] + acc[2];
        }
    }

    float nrm[8], s1 = 0.f, s2 = 0.f;
    #pragma unroll
    for (int s=0;s<8;++s){
        float n = sqrtf(rx[s]*rx[s] + ry[s]*ry[s] + rz[s]*rz[s]);
        nrm[s] = n; s1 += n; s2 += n*n;
    }
    #pragma unroll
    for (int m=1; m<16; m<<=1){
        s1 += __shfl_xor(s1, m);
        s2 += __shfl_xor(s2, m);
    }
    float mu  = s1*(1.f/128.f);
    float var = s2*(1.f/128.f) - mu*mu;
    float inv = rsqrtf(var + 1e-5f);
    #pragma unroll
    for (int s=0;s<8;++s){
        int o = (s>>1)*32 + (s&1)*16 + mrow;
        size_t base = (size_t)p*384 + (size_t)o*3;
        float nh = (nrm[s] - mu)*inv*gamma[o] + beta[o];
        float sc = nh/(nrm[s] + 1e-6f);
        out[base] = rx[s]*sc; out[base+1] = ry[s]*sc; out[base+2] = rz[s]*sc;
    }
}

// ============================================================================
// FUSED attention: scores + softmax + apply in one kernel (one block/point).
// R13: dot_s removed — per-neighbor dots kept in registers, head-group (16-
// lane) shfl_xor reduce -> dsum_s (512 B).  LDS ~15.6 KB -> ~10 blocks/CU.
// v gathered from packed float3 g_vvf rows (1536 B/row, bit-identical f32).
// ============================================================================
__global__ __launch_bounds__(128) void attn_fused(
    float* io, const float* __restrict__ kf,
    const float* __restrict__ sh, const float* __restrict__ dist, const int* __restrict__ idxp,
    const float* __restrict__ gw1, const float* __restrict__ gb1,
    const float* __restrict__ gw2, const float* __restrict__ gb2)
{
    const int p = blockIdx.x, c = threadIdx.x;
    __shared__ __align__(16) float pos_s[16*132];
    __shared__ float sh_s[48];
    __shared__ int   nidx[16];
    __shared__ __align__(16) float w1t[8*132];
    __shared__ float w2_s[64], b1_s[8], b2_s[8];
    __shared__ float u2_s[16*8], logit_s[16*8];
    __shared__ float dsum_s[16*8];
    __shared__ float att_s[128];

    if (c < 16) nidx[c] = idxp[p*16 + c];
    if (c < 48) sh_s[c] = sh[(size_t)p*51 + 3 + c];
    #pragma unroll
    for (int f = c; f < 1024; f += 128){
        int th2 = f >> 7, cc2 = f & 127;
        w1t[th2*132 + cc2] = gw1[cc2*8 + th2];
    }
    if (c < 64) w2_s[c] = gw2[c];
    if (c < 8){ b1_s[c]=gb1[c]; b2_s[c]=gb2[c]; }
    size_t qa = (size_t)p*384 + c*3;
    float qx = io[qa], qy = io[qa+1], qz = io[qa+2];
    __syncthreads();

    float dreg[16];
    #pragma unroll
    for (int n=0;n<16;++n){
        size_t kbase = (size_t)nidx[n]*384 + c*3;
        float kx = kf[kbase], ky = kf[kbase+1], kz = kf[kbase+2];
        dreg[n] = kx*qx + ky*qy + kz*qz;
        pos_s[n*132 + c] = (kx-qx)*sh_s[n*3] + (ky-qy)*sh_s[n*3+1] + (kz-qz)*sh_s[n*3+2];
    }
    // head-group (16-lane) butterfly reduce of dots; lane (c&15)==n writes
    // dsum_s[n*8 + head] (head = c>>4).
    #pragma unroll
    for (int n=0;n<16;++n){
        float v = dreg[n];
        v += __shfl_xor(v, 1);
        v += __shfl_xor(v, 2);
        v += __shfl_xor(v, 4);
        v += __shfl_xor(v, 8);
        if ((c & 15) == n) dsum_s[n*8 + (c>>4)] = v;
    }
    __syncthreads();

    const int tn = c >> 3, th = c & 7;
    float uj = b1_s[th];
    const float* prow = pos_s + tn*132;
    const float* wrow = w1t  + th*132;
    #pragma unroll 8
    for (int cc=0; cc<128; cc+=4){
        float4 pv = *(const float4*)(prow + cc);
        float4 wv = *(const float4*)(wrow + cc);
        uj = fmaf(pv.x, wv.x, uj);
        uj = fmaf(pv.y, wv.y, uj);
        uj = fmaf(pv.z, wv.z, uj);
        uj = fmaf(pv.w, wv.w, uj);
    }
    u2_s[tn*8+th] = fmaxf(uj, 0.f);
    __syncthreads();

    float l = b2_s[th];
    #pragma unroll
    for (int j=0;j<8;++j) l += u2_s[tn*8+j]*w2_s[j*8+th];
    l += dsum_s[tn*8+th] + dist[(size_t)p*128 + tn*8 + th];
    logit_s[tn*8+th] = l * 0.25f;
    __syncthreads();

    if (c < 8){
        float mx = -3.0e38f;
        #pragma unroll
        for (int n=0;n<16;++n) mx = fmaxf(mx, logit_s[n*8+c]);
        float e[16], ssum = 0.f;
        #pragma unroll
        for (int n=0;n<16;++n){ e[n] = __expf(logit_s[n*8+c]-mx); ssum += e[n]; }
        float inv = 1.f/ssum;
        #pragma unroll
        for (int n=0;n<16;++n) att_s[n*8+c] = e[n]*inv;
    }
    __syncthreads();

    // ---- phase 2: apply (v in packed f32 float3 rows) ---------------------
    const int h = c >> 4;
    float ax=0.f, ay=0.f, az=0.f;
    #pragma unroll
    for (int n=0;n<16;++n){
        float wgt = att_s[n*8+h];
        size_t vb = (size_t)nidx[n]*384 + c*3;
        ax += wgt*g_vvf[vb];
        ay += wgt*g_vvf[vb+1];
        az += wgt*g_vvf[vb+2];
    }
    size_t ob = (size_t)p*384 + c*3;
    io[ob] = ax; io[ob+1] = ay; io[ob+2] = az;
}

// ============================================================================
// Fused FF + LN2 via MFMA (grid 1250, 40 KB pool, pre-split weight images).
// ============================================================================
__global__ __launch_bounds__(256,2) void vn_ff_mfma(const float* __restrict__ in,
    const float* __restrict__ l2g, const float* __restrict__ l2b,
    float* __restrict__ out)
{
    __shared__ __align__(16) char pool[40960];
    short* Ws1h = (short*)(pool);             // 2048 shorts
    short* Ws1l = (short*)(pool + 4096);
    short* Wsdh = (short*)(pool + 8192);
    short* Wsdl = (short*)(pool + 12288);
    short* Ws2h = (short*)(pool + 16384);     // 4096 shorts
    short* Ws2l = (short*)(pool + 24576);
    short* Hsh  = (short*)(pool + 32768);     // 2048 shorts
    short* Hsl  = (short*)(pool + 36864);
    short* Ysh  = (short*)(pool);             // scratch overlay
    short* Ysl  = (short*)(pool + 16384);

    const int tid  = threadIdx.x;
    const int wv   = tid >> 6;
    const int lane = tid & 63;
    const int mrow = lane & 15;
    const int kgrp = lane >> 4;
    const int p0   = blockIdx.x * 16;

    for (int f = tid; f < 2048; f += 256){
        int row = (f >> 7)*4 + 3, k = f & 127;
        Ysh[row*128 + k] = 0; Ysl[row*128 + k] = 0;
    }
    #pragma unroll
    for (int t = 0; t < 6; ++t){
        int f = tid + t*256;
        float4 w4 = *(const float4*)(in + (size_t)p0*384 + f*4);
        int e = f*4, pl = e/384, rem = e - pl*384;
        float vv4[4] = {w4.x, w4.y, w4.z, w4.w};
        #pragma unroll
        for (int j=0;j<4;++j){
            int c = (rem+j)/3, i = (rem+j) - c*3;
            int row = pl*4 + i;
            int idx = row*128 + (((c>>3) ^ (row&7)) << 3) + (c&7);
            short h, l; split2(vv4[j], h, l);
            Ysh[idx] = h; Ysl[idx] = l;
        }
    }
    __syncthreads();
    short8 ahf[4], alf[4];
    {
        const int arow = wv*16 + mrow;
        #pragma unroll
        for (int ks=0;ks<4;++ks){
            int slot = ks*4 + kgrp;
            int aoff = arow*128 + ((slot ^ (arow&7)) << 3);
            ahf[ks] = *(const short8*)(Ysh + aoff);
            alf[ks] = *(const short8*)(Ysl + aoff);
        }
    }

    floatx4 acc2[8];
    #pragma unroll
    for (int nt=0;nt<8;++nt) acc2[nt] = (floatx4){0.f,0.f,0.f,0.f};

    for (int ch = 0; ch < 32; ++ch){
        __syncthreads();
        #pragma unroll
        for (int t=0;t<4;++t)
            ((short8*)pool)[tid + t*256] =
                ((const short8*)(g_ff1 + ch*8192))[tid + t*256];
        if ((ch & 1) == 0){
            #pragma unroll
            for (int t=0;t<4;++t)
                ((short8*)(pool + 16384))[tid + t*256] =
                    ((const short8*)(g_ff2 + (ch>>1)*8192))[tid + t*256];
        }
        __syncthreads();

        floatx4 aU = {0.f,0.f,0.f,0.f}, aD = {0.f,0.f,0.f,0.f};
        #pragma unroll
        for (int ks=0;ks<4;++ks){
            int slot = ks*4 + kgrp;
            int boff = mrow*128 + ((slot ^ (mrow&7)) << 3);
            short8 b1h = *(const short8*)(Ws1h + boff);
            short8 b1l = *(const short8*)(Ws1l + boff);
            short8 bdh = *(const short8*)(Wsdh + boff);
            short8 bdl = *(const short8*)(Wsdl + boff);
            aU = __builtin_amdgcn_mfma_f32_16x16x32_bf16(ahf[ks], b1h, aU, 0,0,0);
            aU = __builtin_amdgcn_mfma_f32_16x16x32_bf16(ahf[ks], b1l, aU, 0,0,0);
            aU = __builtin_amdgcn_mfma_f32_16x16x32_bf16(alf[ks], b1h, aU, 0,0,0);
            aD = __builtin_amdgcn_mfma_f32_16x16x32_bf16(ahf[ks], bdh, aD, 0,0,0);
            aD = __builtin_amdgcn_mfma_f32_16x16x32_bf16(ahf[ks], bdl, aD, 0,0,0);
            aD = __builtin_amdgcn_mfma_f32_16x16x32_bf16(alf[ks], bdh, aD, 0,0,0);
        }

        {
            float ux=aU[0], uy=aU[1], uz=aU[2];
            float dx=aD[0], dy=aD[1], dz=aD[2];
            float dot = ux*dx + uy*dy + uz*dz;
            float ksq = dx*dx + dy*dy + dz*dz;
            if (dot < 0.f){
                float fc = dot/(ksq + 1e-6f);
                ux -= fc*dx; uy -= fc*dy; uz -= fc*dz;
            }
            int col  = (ch & 1)*16 + mrow;
            int slot = col >> 3, cl = col & 7;
            float hv[4] = {ux, uy, uz, 0.f};
            #pragma unroll
            for (int r=0;r<4;++r){
                int row = wv*16 + kgrp*4 + r;
                int idx = row*32 + ((slot ^ ((row>>1)&3)) << 3) + cl;
                short h, l; split2(hv[r], h, l);
                Hsh[idx] = h; Hsl[idx] = l;
            }
        }

        if (ch & 1){
            const int arow2 = wv*16 + mrow;
            int aoff = arow2*32 + ((kgrp ^ ((arow2>>1)&3)) << 3);
            short8 ah = *(const short8*)(Hsh + aoff);
            short8 al = *(const short8*)(Hsl + aoff);
            #pragma unroll
            for (int nt=0;nt<8;++nt){
                int bcol = nt*16 + mrow;
                int boff = bcol*32 + ((kgrp ^ ((bcol>>1)&3)) << 3);
                short8 bh = *(const short8*)(Ws2h + boff);
                short8 bl = *(const short8*)(Ws2l + boff);
                acc2[nt] = __builtin_amdgcn_mfma_f32_16x16x32_bf16(ah, bh, acc2[nt], 0,0,0);
                acc2[nt] = __builtin_amdgcn_mfma_f32_16x16x32_bf16(ah, bl, acc2[nt], 0,0,0);
                acc2[nt] = __builtin_amdgcn_mfma_f32_16x16x32_bf16(al, bh, acc2[nt], 0,0,0);
            }
        }
    }

    const int p = p0 + wv*4 + kgrp;
    float nrm[8];
    float s1 = 0.f, s2 = 0.f;
    #pragma unroll
    for (int nt=0;nt<8;++nt){
        int o = nt*16 + mrow;
        size_t base = (size_t)p*384 + (size_t)o*3;
        float rx = in[base]   + acc2[nt][0];
        float ry = in[base+1] + acc2[nt][1];
        float rz = in[base+2] + acc2[nt][2];
        float n = sqrtf(rx*rx + ry*ry + rz*rz);
        nrm[nt] = n;
        s1 += n; s2 += n*n;
    }
    #pragma unroll
    for (int m=1; m<16; m<<=1){
        s1 += __shfl_xor(s1, m);
        s2 += __shfl_xor(s2, m);
    }
    float mu  = s1*(1.f/128.f);
    float var = s2*(1.f/128.f) - mu*mu;
    float inv = rsqrtf(var + 1e-5f);
    #pragma unroll
    for (int nt=0;nt<8;++nt){
        int o = nt*16 + mrow;
        size_t base = (size_t)p*384 + (size_t)o*3;
        float rx = in[base]   + acc2[nt][0];
        float ry = in[base+1] + acc2[nt][1];
        float rz = in[base+2] + acc2[nt][2];
        float nh = (nrm[nt] - mu)*inv*l2g[o] + l2b[o];
        float sc = nh/(nrm[nt] + 1e-6f);
        out[base] = rx*sc; out[base+1] = ry*sc; out[base+2] = rz*sc;
    }
}

// ============================================================================
extern "C" void kernel_launch(void* const* d_in, const int* in_sizes, int n_in,
                              void* d_out, int out_size, void* d_ws, size_t ws_size,
                              hipStream_t stream)
{
    const float* tgt  = (const float*)d_in[0];
    const float* mem  = (const float*)d_in[1];
    const float* sh   = (const float*)d_in[2];
    const float* dist = (const float*)d_in[3];
    const float* Wq   = (const float*)d_in[4];
    const float* Wk   = (const float*)d_in[5];
    const float* Wv   = (const float*)d_in[6];
    const float* Wo   = (const float*)d_in[7];
    const float* gw1  = (const float*)d_in[8];
    const float* gb1  = (const float*)d_in[9];
    const float* gw2  = (const float*)d_in[10];
    const float* gb2  = (const float*)d_in[11];
    const float* ln1g = (const float*)d_in[12];
    const float* ln1b = (const float*)d_in[13];
    const float* ln2g = (const float*)d_in[14];
    const float* ln2b = (const float*)d_in[15];
    const float* fw1  = (const float*)d_in[16];
    const float* fd1  = (const float*)d_in[17];
    const float* fw2  = (const float*)d_in[18];
    const int*   idx  = (const int*)d_in[19];

    float* wsf = (float*)d_ws;
    float* outf = (float*)d_out;

    prep_weights<<<64,256,0,stream>>>(Wq, Wk, Wv, Wo, fw1, fd1, fw2);

    vn_gemm_mfma_t<0><<<1250,256,0,stream>>>(mem, 1, wsf);            // kb = mem@Wk (f32 -> ws)
    vn_gemm_mfma_t<1><<<1250,256,0,stream>>>(mem, 2, nullptr);        // vv = mem@Wv (f32 packed -> g_vvf)
    vn_gemm_mfma_t<0><<<1250,256,0,stream>>>(tgt, 0, outf);           // q  = tgt@Wq (f32 -> d_out)
    // fused attention: logits+softmax+apply; overwrites own q rows with tgt2
    attn_fused<<<PP,128,0,stream>>>(outf, wsf, sh, dist, idx, gw1, gb1, gw2, gb2);
    // fused Wo GEMM + LN1: y = LN1(tgt + tgt2@Wo) -> ws
    vn_gemm_ln_mfma<<<1250,256,0,stream>>>(outf, tgt, ln1g, ln1b, wsf);
    // fused FF + LN2: reads y (ws), writes FINAL output to d_out
    vn_ff_mfma<<<1250,256,0,stream>>>(wsf, ln2g, ln2b, outf);
}